// Round 1
// baseline (1384.194 us; speedup 1.0000x reference)
//
#include <hip/hip_runtime.h>
#include <hip/hip_bf16.h>
#include <stdint.h>

// ---------- types ----------
typedef __bf16  bf16x8  __attribute__((ext_vector_type(8)));
typedef float   f32x4   __attribute__((ext_vector_type(4)));
typedef unsigned short u16x8 __attribute__((ext_vector_type(8)));
typedef unsigned short ushort_t;

__device__ __forceinline__ unsigned short f2b(float f) {
    __hip_bfloat16 h = __float2bfloat16(f);   // RNE
    return *reinterpret_cast<unsigned short*>(&h);
}

// dims
#define BB 8
#define LL 2048
#define DM 64
#define NH 4
#define DK 64

// ---------- K0: pack mask int32 -> bits (k-major, 32 keys/word) ----------
// one thread builds one 32-bit word from 32 consecutive mask ints (int4-vectorized)
__global__ __launch_bounds__(256) void k_maskpack(const int* __restrict__ mask,
                                                  unsigned int* __restrict__ words) {
    int tid = blockIdx.x * 256 + threadIdx.x;        // word index, 1,048,576 total
    const int4* p = reinterpret_cast<const int4*>(mask) + (size_t)tid * 8;
    unsigned int wbits = 0u;
    #pragma unroll
    for (int i = 0; i < 8; i++) {
        int4 v = p[i];
        wbits |= (v.x != 0 ? 1u << (4 * i + 0) : 0u);
        wbits |= (v.y != 0 ? 1u << (4 * i + 1) : 0u);
        wbits |= (v.z != 0 ? 1u << (4 * i + 2) : 0u);
        wbits |= (v.w != 0 ? 1u << (4 * i + 3) : 0u);
    }
    words[tid] = wbits;
}

// ---------- K1: gates S_q,S_k,S_v per batch ----------
__global__ __launch_bounds__(64) void k_gates(const float* __restrict__ u,
                                              const float* s1q, const float* s2q,
                                              const float* s1k, const float* s2k,
                                              const float* s1v, const float* s2v,
                                              float* __restrict__ gates) {
    int b = blockIdx.x, g = blockIdx.y, lane = threadIdx.x;
    const float* s1 = (g == 0) ? s1q : (g == 1) ? s1k : s1v;
    const float* s2 = (g == 0) ? s2q : (g == 1) ? s2k : s2v;
    float ur = u[b * 64 + lane];
    float acc = 0.f;
    for (int j = 0; j < 64; j++) {
        float uj = __shfl(ur, j, 64);
        if (lane < 32) acc += uj * s1[j * 32 + lane];
    }
    float r = (lane < 32) ? fmaxf(acc, 0.f) * s2[lane] : 0.f;
    for (int m = 32; m >= 1; m >>= 1) r += __shfl_xor(r, m, 64);
    if (lane == 0) gates[b * 3 + g] = r;
}

// ---------- K2: projections ----------
// Qe [b,h,L,128] (scaled 1/8), Ke [b,h,L,128], VeT [b,h,64,L] = (V+uV)^T  (bf16)
__global__ __launch_bounds__(256) void k_proj(const float* __restrict__ x,
                                              const float* __restrict__ wq,
                                              const float* __restrict__ wk,
                                              const float* __restrict__ wv,
                                              const float* __restrict__ uqw,
                                              const float* __restrict__ ukw,
                                              const float* __restrict__ uvw,
                                              const float* __restrict__ gates,
                                              ushort_t* __restrict__ Qe,
                                              ushort_t* __restrict__ Ke,
                                              ushort_t* __restrict__ VeT) {
    int lt = blockIdx.x, b = blockIdx.y, t = threadIdx.x;
    int l0 = lt * 32;
    __shared__ float lx[32][68];     // +4 pad keeps 16B alignment of float4 rows
    __shared__ float luv[32][68];
    #pragma unroll
    for (int i = 0; i < 2; i++) {      // stage x tile: 32x64 floats
        int id = t + i * 256;          // 0..511
        int r = id >> 4, c4 = id & 15;
        float4 v = *(const float4*)&x[((b * LL) + l0 + r) * 64 + c4 * 4];
        *(float4*)&lx[r][c4 * 4] = v;
    }
    __syncthreads();
    float Sq = gates[b * 3 + 0], Sk = gates[b * 3 + 1], Sv = gates[b * 3 + 2];
    // u-projections (waves 0..2), float4 over j
    if (t < 192) {
        int m = t >> 6, d = t & 63;
        const float* uw = (m == 0) ? uqw : (m == 1) ? ukw : uvw;
        float acc[32];
        #pragma unroll
        for (int r = 0; r < 32; r++) acc[r] = 0.f;
        for (int j = 0; j < 64; j += 4) {
            float w0 = uw[(j + 0) * 64 + d], w1 = uw[(j + 1) * 64 + d];
            float w2 = uw[(j + 2) * 64 + d], w3 = uw[(j + 3) * 64 + d];
            #pragma unroll
            for (int r = 0; r < 32; r++) {
                float4 xv = *(const float4*)&lx[r][j];
                acc[r] += xv.x * w0 + xv.y * w1 + xv.z * w2 + xv.w * w3;
            }
        }
        if (m == 2) {
            #pragma unroll
            for (int r = 0; r < 32; r++) luv[r][d] = acc[r] * Sv;
        } else {
            ushort_t* dst = (m == 0) ? Qe : Ke;
            float sc = (m == 0) ? Sq * 0.125f : Sk;
            for (int r = 0; r < 32; r++) {
                unsigned short v = f2b(acc[r] * sc);
                int base = ((b * NH) * LL + l0 + r) * 128 + 64 + d;
                #pragma unroll
                for (int hh2 = 0; hh2 < 4; hh2++) dst[base + hh2 * (LL * 128)] = v;
            }
        }
    }
    __syncthreads();
    // fused head projections: thread = output column c (q,k,v simultaneously)
    int c = t, hh = c >> 6, d = c & 63;
    float aq_[32], ak_[32], av_[32];
    #pragma unroll
    for (int r = 0; r < 32; r++) { aq_[r] = 0.f; ak_[r] = 0.f; av_[r] = 0.f; }
    for (int j = 0; j < 64; j += 4) {
        float q0w = wq[(j + 0) * 256 + c], q1w = wq[(j + 1) * 256 + c];
        float q2w = wq[(j + 2) * 256 + c], q3w = wq[(j + 3) * 256 + c];
        float k0w = wk[(j + 0) * 256 + c], k1w = wk[(j + 1) * 256 + c];
        float k2w = wk[(j + 2) * 256 + c], k3w = wk[(j + 3) * 256 + c];
        float v0w = wv[(j + 0) * 256 + c], v1w = wv[(j + 1) * 256 + c];
        float v2w = wv[(j + 2) * 256 + c], v3w = wv[(j + 3) * 256 + c];
        #pragma unroll
        for (int r = 0; r < 32; r++) {
            float4 xv = *(const float4*)&lx[r][j];
            aq_[r] += xv.x * q0w + xv.y * q1w + xv.z * q2w + xv.w * q3w;
            ak_[r] += xv.x * k0w + xv.y * k1w + xv.z * k2w + xv.w * k3w;
            av_[r] += xv.x * v0w + xv.y * v1w + xv.z * v2w + xv.w * v3w;
        }
    }
    int outbase = (b * NH + hh) * LL + l0;
    #pragma unroll
    for (int r = 0; r < 32; r++) Qe[(outbase + r) * 128 + d] = f2b(aq_[r] * 0.125f);
    #pragma unroll
    for (int r = 0; r < 32; r++) Ke[(outbase + r) * 128 + d] = f2b(ak_[r]);
    // VeT: row d of [b,h,64,L]; 32 consecutive l per thread -> 4x vectorized stores
    long vbase = ((long)(b * NH + hh) * 64 + d) * LL + l0;
    #pragma unroll
    for (int rb = 0; rb < 4; rb++) {
        u16x8 vv;
        #pragma unroll
        for (int k = 0; k < 8; k++) {
            int r = rb * 8 + k;
            vv[k] = f2b(av_[r] + luv[r][d]);
        }
        *(u16x8*)&VeT[vbase + rb * 8] = vv;
    }
}

// ---------- K3: attention core (two-pass over K, barrier-free k-loops) ----------
// grid (32 qtiles, 4 heads, 8 batches), 256 threads (4 waves x 16 q-rows)
// Ke/VeT MFMA fragments are read directly from global (L1/L2-served); no per-tile
// LDS staging, no __syncthreads in the k-loops. XCD swizzle: batch b -> XCD b.
__global__ __launch_bounds__(256) void k_attn(const ushort_t* __restrict__ Qe,
                                              const ushort_t* __restrict__ Ke,
                                              const ushort_t* __restrict__ VeT,
                                              const unsigned int* __restrict__ mwords,
                                              float* __restrict__ ctx,
                                              float* __restrict__ attn) {
    // bijective XCD swizzle over 1024 blocks: lin%8 (XCD) picks the batch
    int lin = blockIdx.x + 32 * blockIdx.y + 128 * blockIdx.z;
    int sw  = ((lin & 7) << 7) | (lin >> 3);
    int qt = sw & 31, h = (sw >> 5) & 3, b = sw >> 7;

    int t = threadIdx.x, w = t >> 6, lane = t & 63, quad = lane >> 4, l15 = lane & 15;
    int q0 = qt * 64;
    int bh = b * NH + h;
    const ushort_t* QeB = Qe + (long)bh * LL * 128;
    const ushort_t* KeB = Ke + (long)bh * LL * 128;
    const ushort_t* VtB = VeT + (long)bh * 64 * LL;
    float* attnB = attn + (long)bh * LL * LL;
    const unsigned int* mB = mwords + (long)(b * LL) * 64;

    __shared__ unsigned int  smask[64][66];   // q-tile mask words, +2 pad
    __shared__ unsigned short sPb[4][16][72]; // per-wave P tile [q][key] bf16

    // stage this q-tile's mask bits (64 rows x 64 words) -- once
    #pragma unroll
    for (int i = 0; i < 16; i++) {
        int id = t + i * 256;
        smask[id >> 6][id & 63] = mB[(q0 + (id >> 6)) * 64 + (id & 63)];
    }

    // Q fragments for this wave's 16 rows (resident whole kernel)
    bf16x8 aq[4];
    int qrow = q0 + w * 16 + l15;
    #pragma unroll
    for (int c = 0; c < 4; c++)
        aq[c] = *(const bf16x8*)&QeB[qrow * 128 + c * 32 + quad * 8];

    __syncthreads();   // only barrier: smask visibility

    float lsum[4] = {0.f, 0.f, 0.f, 0.f};
    int mrow = w * 16 + quad * 4;              // this lane's first mask row

    // ---- pass A: row sums (no stores, no barriers) ----
    for (int kt = 0; kt < 32; kt++) {
        int k0 = kt * 64;
        #pragma unroll
        for (int nb = 0; nb < 4; nb++) {
            f32x4 s = (f32x4){0.f, 0.f, 0.f, 0.f};
            #pragma unroll
            for (int c = 0; c < 4; c++) {
                bf16x8 kb = *(const bf16x8*)&KeB[(k0 + nb * 16 + l15) * 128 + c * 32 + quad * 8];
                s = __builtin_amdgcn_mfma_f32_16x16x32_bf16(aq[c], kb, s, 0, 0, 0);
            }
            #pragma unroll
            for (int reg = 0; reg < 4; reg++) {
                unsigned int word = smask[mrow + reg][kt * 2 + (nb >> 1)];
                unsigned int bit = (word >> ((nb & 1) * 16 + l15)) & 1u;
                lsum[reg] += bit ? 0.f : __expf(fminf(s[reg], 60.f));
            }
        }
    }
    // row sums: reduce across the 16 lanes holding a row's columns
    float inv[4];
    #pragma unroll
    for (int reg = 0; reg < 4; reg++) {
        float v = lsum[reg];
        #pragma unroll
        for (int m = 1; m < 16; m <<= 1) v += __shfl_xor(v, m, 16);
        inv[reg] = (v > 0.f) ? 1.f / v : 0.f;
    }

    // ---- pass B: normalized attn store + PV (no barriers) ----
    f32x4 cacc[4];
    #pragma unroll
    for (int db = 0; db < 4; db++) cacc[db] = (f32x4){0.f, 0.f, 0.f, 0.f};

    for (int kt = 0; kt < 32; kt++) {
        int k0 = kt * 64;
        #pragma unroll
        for (int nb = 0; nb < 4; nb++) {
            f32x4 s = (f32x4){0.f, 0.f, 0.f, 0.f};
            #pragma unroll
            for (int c = 0; c < 4; c++) {
                bf16x8 kb = *(const bf16x8*)&KeB[(k0 + nb * 16 + l15) * 128 + c * 32 + quad * 8];
                s = __builtin_amdgcn_mfma_f32_16x16x32_bf16(aq[c], kb, s, 0, 0, 0);
            }
            #pragma unroll
            for (int reg = 0; reg < 4; reg++) {
                unsigned int word = smask[mrow + reg][kt * 2 + (nb >> 1)];
                unsigned int bit = (word >> ((nb & 1) * 16 + l15)) & 1u;
                float p = bit ? 0.f : __expf(fminf(s[reg], 60.f));
                sPb[w][quad * 4 + reg][nb * 16 + l15] = f2b(p);
                __builtin_nontemporal_store(p * inv[reg],
                    &attnB[(long)(q0 + mrow + reg) * LL + k0 + nb * 16 + l15]);
            }
        }
        // ctx += P @ Ve   (unnormalized P; normalized at the end)
        // V fragments straight from global VeT [d][l] -- no transpose staging
        #pragma unroll
        for (int db = 0; db < 4; db++) {
            #pragma unroll
            for (int c2 = 0; c2 < 2; c2++) {
                bf16x8 a  = *(const bf16x8*)&sPb[w][l15][c2 * 32 + quad * 8];
                bf16x8 bb = *(const bf16x8*)&VtB[(db * 16 + l15) * LL + k0 + c2 * 32 + quad * 8];
                cacc[db] = __builtin_amdgcn_mfma_f32_16x16x32_bf16(a, bb, cacc[db], 0, 0, 0);
            }
        }
    }
    // normalized ctx -> ws [b,L,256] fp32
    #pragma unroll
    for (int db = 0; db < 4; db++)
        #pragma unroll
        for (int reg = 0; reg < 4; reg++) {
            int qr = q0 + mrow + reg;
            ctx[((long)(b * LL) + qr) * 256 + h * 64 + db * 16 + l15] = cacc[db][reg] * inv[reg];
        }
}

// ---------- K5: fc + residual + LN1 + FFN + LN2 ----------
__global__ __launch_bounds__(256) void k_epi(const float* __restrict__ ctx,
                                             const float* __restrict__ x,
                                             const float* __restrict__ fcw,
                                             const float* __restrict__ g1,
                                             const float* __restrict__ b1,
                                             const float* __restrict__ f1,
                                             const float* __restrict__ f2,
                                             const float* __restrict__ g2,
                                             const float* __restrict__ b2w,
                                             float* __restrict__ res) {
    int w = threadIdx.x >> 6, lane = threadIdx.x & 63;
    int row = blockIdx.x * 4 + w;
    const float* cr = ctx + (long)row * 256;
    float creg[4];
    #pragma unroll
    for (int i = 0; i < 4; i++) creg[i] = cr[i * 64 + lane];
    float acc = 0.f;
    #pragma unroll
    for (int j = 0; j < 256; j++) {
        float cj = __shfl(creg[j >> 6], j & 63, 64);
        acc += cj * fcw[j * 64 + lane];
    }
    float val = acc + x[row * 64 + lane];
    float mu = val;
    #pragma unroll
    for (int m = 1; m < 64; m <<= 1) mu += __shfl_xor(mu, m, 64);
    mu *= (1.f / 64.f);
    float d0 = val - mu;
    float var = d0 * d0;
    #pragma unroll
    for (int m = 1; m < 64; m <<= 1) var += __shfl_xor(var, m, 64);
    var *= (1.f / 64.f);
    float enc = d0 * rsqrtf(var + 1e-5f) * g1[lane] + b1[lane];
    float a1 = 0.f;
    #pragma unroll
    for (int j = 0; j < 64; j++) a1 += __shfl(enc, j, 64) * f1[j * 64 + lane];
    float hrel = fmaxf(a1, 0.f);
    float a2 = 0.f;
    #pragma unroll
    for (int j = 0; j < 64; j++) a2 += __shfl(hrel, j, 64) * f2[j * 64 + lane];
    float v2 = a2 + enc;
    float mu2 = v2;
    #pragma unroll
    for (int m = 1; m < 64; m <<= 1) mu2 += __shfl_xor(mu2, m, 64);
    mu2 *= (1.f / 64.f);
    float d2 = v2 - mu2;
    float var2 = d2 * d2;
    #pragma unroll
    for (int m = 1; m < 64; m <<= 1) var2 += __shfl_xor(var2, m, 64);
    var2 *= (1.f / 64.f);
    float outv = d2 * rsqrtf(var2 + 1e-5f) * g2[lane] + b2w[lane];
    res[row * 64 + lane] = outv;
}

// ---------- launch ----------
extern "C" void kernel_launch(void* const* d_in, const int* in_sizes, int n_in,
                              void* d_out, int out_size, void* d_ws, size_t ws_size,
                              hipStream_t stream) {
    const float* x    = (const float*)d_in[0];
    const int*   mask = (const int*)d_in[1];
    const float* u    = (const float*)d_in[2];
    const float* wq   = (const float*)d_in[3];
    const float* wk   = (const float*)d_in[4];
    const float* wv   = (const float*)d_in[5];
    const float* uqw  = (const float*)d_in[6];
    const float* ukw  = (const float*)d_in[7];
    const float* uvw  = (const float*)d_in[8];
    const float* sq1  = (const float*)d_in[9];
    const float* sq2  = (const float*)d_in[10];
    const float* sk1  = (const float*)d_in[11];
    const float* sk2  = (const float*)d_in[12];
    const float* sv1  = (const float*)d_in[13];
    const float* sv2  = (const float*)d_in[14];
    const float* fcw  = (const float*)d_in[15];
    const float* g1   = (const float*)d_in[16];
    const float* b1   = (const float*)d_in[17];
    const float* f1   = (const float*)d_in[18];
    const float* f2   = (const float*)d_in[19];
    const float* g2   = (const float*)d_in[20];
    const float* b2w  = (const float*)d_in[21];

    char* ws = (char*)d_ws;
    float*        gates  = (float*)(ws + 0);
    unsigned int* mwords = (unsigned int*)(ws + 4096);              // 4,194,304 B
    ushort_t*     Qe     = (ushort_t*)(ws + 4198400);               // 16,777,216 B
    ushort_t*     Ke     = (ushort_t*)(ws + 20975616);              // 16,777,216 B
    ushort_t*     VeT    = (ushort_t*)(ws + 37752832);              //  8,388,608 B
    float*        ctx    = (float*)(ws + 46141440);                 // 16,777,216 B (end ~63 MB)

    float* res  = (float*)d_out;
    float* attn = (float*)d_out + (size_t)BB * LL * DM;             // offset 1,048,576 elems

    k_maskpack<<<dim3(4096), dim3(256), 0, stream>>>(mask, mwords);
    k_gates<<<dim3(8, 3), dim3(64), 0, stream>>>(u, sq1, sq2, sk1, sk2, sv1, sv2, gates);
    k_proj<<<dim3(64, 8), dim3(256), 0, stream>>>(x, wq, wk, wv, uqw, ukw, uvw, gates, Qe, Ke, VeT);
    k_attn<<<dim3(32, 4, 8), dim3(256), 0, stream>>>(Qe, Ke, VeT, mwords, ctx, attn);
    k_epi<<<dim3(4096), dim3(256), 0, stream>>>(ctx, x, fcw, g1, b1, f1, f2, g2, b2w, res);
}

// Round 2
// 1005.878 us; speedup vs baseline: 1.3761x; 1.3761x over previous
//
#include <hip/hip_runtime.h>
#include <hip/hip_bf16.h>
#include <stdint.h>

// ---------- types ----------
typedef __bf16  bf16x8  __attribute__((ext_vector_type(8)));
typedef float   f32x4   __attribute__((ext_vector_type(4)));
typedef unsigned short u16x8 __attribute__((ext_vector_type(8)));
typedef unsigned short ushort_t;

__device__ __forceinline__ unsigned short f2b(float f) {
    __hip_bfloat16 h = __float2bfloat16(f);   // RNE
    return *reinterpret_cast<unsigned short*>(&h);
}

// async 16B global->LDS (direct-to-LDS DMA; LDS dest is wave-uniform base + lane*16)
__device__ __forceinline__ void cp16(const void* g, void* l) {
    __builtin_amdgcn_global_load_lds(
        (const __attribute__((address_space(1))) unsigned int*)g,
        (__attribute__((address_space(3))) unsigned int*)l,
        16, 0, 0);
}

// dims
#define BB 8
#define LL 2048
#define DM 64
#define NH 4
#define DK 64

// ---------- K0: pack mask int32 -> bits (k-major, 32 keys/word) ----------
__global__ __launch_bounds__(256) void k_maskpack(const int* __restrict__ mask,
                                                  unsigned int* __restrict__ words) {
    int tid = blockIdx.x * 256 + threadIdx.x;        // word index, 1,048,576 total
    const int4* p = reinterpret_cast<const int4*>(mask) + (size_t)tid * 8;
    unsigned int wbits = 0u;
    #pragma unroll
    for (int i = 0; i < 8; i++) {
        int4 v = p[i];
        wbits |= (v.x != 0 ? 1u << (4 * i + 0) : 0u);
        wbits |= (v.y != 0 ? 1u << (4 * i + 1) : 0u);
        wbits |= (v.z != 0 ? 1u << (4 * i + 2) : 0u);
        wbits |= (v.w != 0 ? 1u << (4 * i + 3) : 0u);
    }
    words[tid] = wbits;
}

// ---------- K1: gates S_q,S_k,S_v per batch ----------
__global__ __launch_bounds__(64) void k_gates(const float* __restrict__ u,
                                              const float* s1q, const float* s2q,
                                              const float* s1k, const float* s2k,
                                              const float* s1v, const float* s2v,
                                              float* __restrict__ gates) {
    int b = blockIdx.x, g = blockIdx.y, lane = threadIdx.x;
    const float* s1 = (g == 0) ? s1q : (g == 1) ? s1k : s1v;
    const float* s2 = (g == 0) ? s2q : (g == 1) ? s2k : s2v;
    float ur = u[b * 64 + lane];
    float acc = 0.f;
    for (int j = 0; j < 64; j++) {
        float uj = __shfl(ur, j, 64);
        if (lane < 32) acc += uj * s1[j * 32 + lane];
    }
    float r = (lane < 32) ? fmaxf(acc, 0.f) * s2[lane] : 0.f;
    for (int m = 32; m >= 1; m >>= 1) r += __shfl_xor(r, m, 64);
    if (lane == 0) gates[b * 3 + g] = r;
}

// ---------- K2: projections ----------
// Qe [b,h,L,128] linear (scaled 1/8).
// Ke [b,h,L,128] with col XOR-swizzle: element (l,c) stored at c ^ ((l&7)<<3).
// VeT [b,h,64,L] = (V+uV)^T with per-64-block col swizzle: within each 64-col block,
//   element (d,l) stored at (l&63) ^ ((d&7)<<3).
// Swizzles make the LDS tiles (linear byte-copies of these regions) bank-conflict-free
// under the MFMA fragment read pattern in k_attn.
__global__ __launch_bounds__(256) void k_proj(const float* __restrict__ x,
                                              const float* __restrict__ wq,
                                              const float* __restrict__ wk,
                                              const float* __restrict__ wv,
                                              const float* __restrict__ uqw,
                                              const float* __restrict__ ukw,
                                              const float* __restrict__ uvw,
                                              const float* __restrict__ gates,
                                              ushort_t* __restrict__ Qe,
                                              ushort_t* __restrict__ Ke,
                                              ushort_t* __restrict__ VeT) {
    int lt = blockIdx.x, b = blockIdx.y, t = threadIdx.x;
    int l0 = lt * 32;
    __shared__ float lx[32][68];
    __shared__ float luv[32][68];
    #pragma unroll
    for (int i = 0; i < 2; i++) {      // stage x tile: 32x64 floats
        int id = t + i * 256;
        int r = id >> 4, c4 = id & 15;
        float4 v = *(const float4*)&x[((b * LL) + l0 + r) * 64 + c4 * 4];
        *(float4*)&lx[r][c4 * 4] = v;
    }
    __syncthreads();
    float Sq = gates[b * 3 + 0], Sk = gates[b * 3 + 1], Sv = gates[b * 3 + 2];
    // u-projections (waves 0..2)
    if (t < 192) {
        int m = t >> 6, d = t & 63;
        const float* uw = (m == 0) ? uqw : (m == 1) ? ukw : uvw;
        float acc[32];
        #pragma unroll
        for (int r = 0; r < 32; r++) acc[r] = 0.f;
        for (int j = 0; j < 64; j += 4) {
            float w0 = uw[(j + 0) * 64 + d], w1 = uw[(j + 1) * 64 + d];
            float w2 = uw[(j + 2) * 64 + d], w3 = uw[(j + 3) * 64 + d];
            #pragma unroll
            for (int r = 0; r < 32; r++) {
                float4 xv = *(const float4*)&lx[r][j];
                acc[r] += xv.x * w0 + xv.y * w1 + xv.z * w2 + xv.w * w3;
            }
        }
        if (m == 2) {
            #pragma unroll
            for (int r = 0; r < 32; r++) luv[r][d] = acc[r] * Sv;
        } else if (m == 0) {
            for (int r = 0; r < 32; r++) {
                unsigned short v = f2b(acc[r] * Sq * 0.125f);
                int base = ((b * NH) * LL + l0 + r) * 128 + 64 + d;
                #pragma unroll
                for (int hh2 = 0; hh2 < 4; hh2++) Qe[base + hh2 * (LL * 128)] = v;
            }
        } else {
            for (int r = 0; r < 32; r++) {
                unsigned short v = f2b(acc[r] * Sk);
                int col = 64 + (d ^ ((r & 7) << 3));   // Ke swizzle (row&7 == r&7)
                int base = ((b * NH) * LL + l0 + r) * 128 + col;
                #pragma unroll
                for (int hh2 = 0; hh2 < 4; hh2++) Ke[base + hh2 * (LL * 128)] = v;
            }
        }
    }
    __syncthreads();
    // fused head projections: thread = output column c (q,k,v simultaneously)
    int c = t, hh = c >> 6, d = c & 63;
    float aq_[32], ak_[32], av_[32];
    #pragma unroll
    for (int r = 0; r < 32; r++) { aq_[r] = 0.f; ak_[r] = 0.f; av_[r] = 0.f; }
    for (int j = 0; j < 64; j += 4) {
        float q0w = wq[(j + 0) * 256 + c], q1w = wq[(j + 1) * 256 + c];
        float q2w = wq[(j + 2) * 256 + c], q3w = wq[(j + 3) * 256 + c];
        float k0w = wk[(j + 0) * 256 + c], k1w = wk[(j + 1) * 256 + c];
        float k2w = wk[(j + 2) * 256 + c], k3w = wk[(j + 3) * 256 + c];
        float v0w = wv[(j + 0) * 256 + c], v1w = wv[(j + 1) * 256 + c];
        float v2w = wv[(j + 2) * 256 + c], v3w = wv[(j + 3) * 256 + c];
        #pragma unroll
        for (int r = 0; r < 32; r++) {
            float4 xv = *(const float4*)&lx[r][j];
            aq_[r] += xv.x * q0w + xv.y * q1w + xv.z * q2w + xv.w * q3w;
            ak_[r] += xv.x * k0w + xv.y * k1w + xv.z * k2w + xv.w * k3w;
            av_[r] += xv.x * v0w + xv.y * v1w + xv.z * v2w + xv.w * v3w;
        }
    }
    int outbase = (b * NH + hh) * LL + l0;
    #pragma unroll
    for (int r = 0; r < 32; r++) Qe[(outbase + r) * 128 + d] = f2b(aq_[r] * 0.125f);
    #pragma unroll
    for (int r = 0; r < 32; r++)
        Ke[(outbase + r) * 128 + (d ^ ((r & 7) << 3))] = f2b(ak_[r]);
    // VeT with swizzle: 8-element blocks permuted inside each 64-col block
    long vbase = ((long)(b * NH + hh) * 64 + d) * LL;
    int lblk = l0 & ~63, loff = l0 & 63;
    #pragma unroll
    for (int rb = 0; rb < 4; rb++) {
        u16x8 vv;
        #pragma unroll
        for (int k = 0; k < 8; k++) {
            int r = rb * 8 + k;
            vv[k] = f2b(av_[r] + luv[r][d]);
        }
        int off = (loff + rb * 8) ^ ((d & 7) << 3);
        *(u16x8*)&VeT[vbase + lblk + off] = vv;
    }
}

// ---------- K3: attention core (two-pass, async double-buffered LDS) ----------
// grid (32 qtiles, 4 heads, 8 batches), 256 threads (4 waves x 16 q-rows)
// One barrier per k-tile; prefetch kt+1 issued right after the barrier so it has a
// full compute phase to land. Swizzled Ke/VeT make ds_read_b128 2-way (free).
__global__ __launch_bounds__(256) void k_attn(const ushort_t* __restrict__ Qe,
                                              const ushort_t* __restrict__ Ke,
                                              const ushort_t* __restrict__ VeT,
                                              const unsigned int* __restrict__ mwords,
                                              float* __restrict__ ctx,
                                              float* __restrict__ attn) {
    // bijective XCD swizzle over 1024 blocks: lin%8 (XCD) picks the batch
    int lin = blockIdx.x + 32 * blockIdx.y + 128 * blockIdx.z;
    int sw  = ((lin & 7) << 7) | (lin >> 3);
    int qt = sw & 31, h = (sw >> 5) & 3, b = sw >> 7;

    int t = threadIdx.x, w = t >> 6, lane = t & 63, quad = lane >> 4, l15 = lane & 15;
    int q0 = qt * 64;
    int bh = b * NH + h;
    const ushort_t* QeB = Qe + (long)bh * LL * 128;
    const ushort_t* KeB = Ke + (long)bh * LL * 128;
    const ushort_t* VtB = VeT + (long)bh * 64 * LL;
    float* attnB = attn + (long)bh * LL * LL;
    const unsigned int* mB = mwords + (long)(b * LL) * 64;

    __shared__ ushort_t sKe[2][64 * 128];     // 32 KB dbuf (linear, swizzled content)
    __shared__ ushort_t sVT[2][64 * 64];      // 16 KB dbuf
    __shared__ unsigned int smask[64][66];    // 16.9 KB
    __shared__ ushort_t sPb[4][16][72];       //  9.2 KB

    // stage this q-tile's mask bits (64 rows x 64 words) -- once
    #pragma unroll
    for (int i = 0; i < 16; i++) {
        int id = t + i * 256;
        smask[id >> 6][id & 63] = mB[(q0 + (id >> 6)) * 64 + (id & 63)];
    }

    // Q fragments for this wave's 16 rows (Qe is linear/unswizzled)
    bf16x8 aq[4];
    int qrow = q0 + w * 16 + l15;
    #pragma unroll
    for (int c = 0; c < 4; c++)
        aq[c] = *(const bf16x8*)&QeB[qrow * 128 + c * 32 + quad * 8];

    int swz = (l15 & 7) << 3;                  // element XOR for swizzled LDS reads
    int mrow = w * 16 + quad * 4;
    float lsum[4] = {0.f, 0.f, 0.f, 0.f};

    // ---- pass A: row sums ----
    // prologue: async-stage Ke tile 0 -> buf0
    #pragma unroll
    for (int i = 0; i < 4; i++) {
        int off = (t + i * 256) * 16;
        cp16((const char*)KeB + off, (char*)&sKe[0][0] + off);
    }
    for (int kt = 0; kt < 32; kt++) {
        int cur = kt & 1;
        __syncthreads();                       // tile kt resident; smask visible (kt=0)
        if (kt < 31) {                         // prefetch kt+1 (lands during compute)
            size_t gb = (size_t)(kt + 1) * 64 * 256;
            #pragma unroll
            for (int i = 0; i < 4; i++) {
                int off = (t + i * 256) * 16;
                cp16((const char*)KeB + gb + off, (char*)&sKe[cur ^ 1][0] + off);
            }
        }
        #pragma unroll
        for (int nb = 0; nb < 4; nb++) {
            f32x4 s = (f32x4){0.f, 0.f, 0.f, 0.f};
            #pragma unroll
            for (int c = 0; c < 4; c++) {
                bf16x8 kb = *(const bf16x8*)&sKe[cur][(nb * 16 + l15) * 128 + ((c * 32 + quad * 8) ^ swz)];
                s = __builtin_amdgcn_mfma_f32_16x16x32_bf16(aq[c], kb, s, 0, 0, 0);
            }
            #pragma unroll
            for (int reg = 0; reg < 4; reg++) {
                unsigned int word = smask[mrow + reg][kt * 2 + (nb >> 1)];
                unsigned int bit = (word >> ((nb & 1) * 16 + l15)) & 1u;
                lsum[reg] += bit ? 0.f : __expf(fminf(s[reg], 60.f));
            }
        }
    }
    // row sums: reduce across the 16 lanes holding a row's columns
    float inv[4];
    #pragma unroll
    for (int reg = 0; reg < 4; reg++) {
        float v = lsum[reg];
        #pragma unroll
        for (int m = 1; m < 16; m <<= 1) v += __shfl_xor(v, m, 16);
        inv[reg] = (v > 0.f) ? 1.f / v : 0.f;
    }

    // ---- pass B: normalized attn store + PV ----
    f32x4 cacc[4];
    #pragma unroll
    for (int db = 0; db < 4; db++) cacc[db] = (f32x4){0.f, 0.f, 0.f, 0.f};

    // prologue: tile 0 of Ke + VeT (safe: all waves past pass-A kt=31 barrier,
    // so buf0's pass-A readers are done; sVT untouched in pass A)
    #pragma unroll
    for (int i = 0; i < 4; i++) {
        int off = (t + i * 256) * 16;
        cp16((const char*)KeB + off, (char*)&sKe[0][0] + off);
    }
    #pragma unroll
    for (int i = 0; i < 2; i++) {
        int off = (t + i * 256) * 16;          // LDS byte offset in 8 KB tile
        int d = off >> 7, cb = off & 127;      // row d (0..63), col byte
        cp16((const char*)VtB + (size_t)d * (LL * 2) + cb, (char*)&sVT[0][0] + off);
    }
    for (int kt = 0; kt < 32; kt++) {
        int cur = kt & 1;
        int k0 = kt * 64;
        __syncthreads();
        if (kt < 31) {
            size_t gKe = (size_t)(k0 + 64) * 256;
            #pragma unroll
            for (int i = 0; i < 4; i++) {
                int off = (t + i * 256) * 16;
                cp16((const char*)KeB + gKe + off, (char*)&sKe[cur ^ 1][0] + off);
            }
            #pragma unroll
            for (int i = 0; i < 2; i++) {
                int off = (t + i * 256) * 16;
                int d = off >> 7, cb = off & 127;
                cp16((const char*)VtB + (size_t)d * (LL * 2) + (size_t)(k0 + 64) * 2 + cb,
                     (char*)&sVT[cur ^ 1][0] + off);
            }
        }
        #pragma unroll
        for (int nb = 0; nb < 4; nb++) {
            f32x4 s = (f32x4){0.f, 0.f, 0.f, 0.f};
            #pragma unroll
            for (int c = 0; c < 4; c++) {
                bf16x8 kb = *(const bf16x8*)&sKe[cur][(nb * 16 + l15) * 128 + ((c * 32 + quad * 8) ^ swz)];
                s = __builtin_amdgcn_mfma_f32_16x16x32_bf16(aq[c], kb, s, 0, 0, 0);
            }
            #pragma unroll
            for (int reg = 0; reg < 4; reg++) {
                unsigned int word = smask[mrow + reg][kt * 2 + (nb >> 1)];
                unsigned int bit = (word >> ((nb & 1) * 16 + l15)) & 1u;
                float p = bit ? 0.f : __expf(fminf(s[reg], 60.f));
                sPb[w][quad * 4 + reg][nb * 16 + l15] = f2b(p);
                __builtin_nontemporal_store(p * inv[reg],
                    &attnB[(long)(q0 + mrow + reg) * LL + k0 + nb * 16 + l15]);
            }
        }
        // ctx += P @ Ve (unnormalized P; normalized at the end)
        #pragma unroll
        for (int db = 0; db < 4; db++) {
            #pragma unroll
            for (int c2 = 0; c2 < 2; c2++) {
                bf16x8 a  = *(const bf16x8*)&sPb[w][l15][c2 * 32 + quad * 8];
                bf16x8 bb = *(const bf16x8*)&sVT[cur][(db * 16 + l15) * 64 + ((c2 * 32 + quad * 8) ^ swz)];
                cacc[db] = __builtin_amdgcn_mfma_f32_16x16x32_bf16(a, bb, cacc[db], 0, 0, 0);
            }
        }
    }
    // normalized ctx -> ws [b,L,256] fp32
    #pragma unroll
    for (int db = 0; db < 4; db++)
        #pragma unroll
        for (int reg = 0; reg < 4; reg++) {
            int qr = q0 + mrow + reg;
            ctx[((long)(b * LL) + qr) * 256 + h * 64 + db * 16 + l15] = cacc[db][reg] * inv[reg];
        }
}

// ---------- K5: fc + residual + LN1 + FFN + LN2 ----------
__global__ __launch_bounds__(256) void k_epi(const float* __restrict__ ctx,
                                             const float* __restrict__ x,
                                             const float* __restrict__ fcw,
                                             const float* __restrict__ g1,
                                             const float* __restrict__ b1,
                                             const float* __restrict__ f1,
                                             const float* __restrict__ f2,
                                             const float* __restrict__ g2,
                                             const float* __restrict__ b2w,
                                             float* __restrict__ res) {
    int w = threadIdx.x >> 6, lane = threadIdx.x & 63;
    int row = blockIdx.x * 4 + w;
    const float* cr = ctx + (long)row * 256;
    float creg[4];
    #pragma unroll
    for (int i = 0; i < 4; i++) creg[i] = cr[i * 64 + lane];
    float acc = 0.f;
    #pragma unroll
    for (int j = 0; j < 256; j++) {
        float cj = __shfl(creg[j >> 6], j & 63, 64);
        acc += cj * fcw[j * 64 + lane];
    }
    float val = acc + x[row * 64 + lane];
    float mu = val;
    #pragma unroll
    for (int m = 1; m < 64; m <<= 1) mu += __shfl_xor(mu, m, 64);
    mu *= (1.f / 64.f);
    float d0 = val - mu;
    float var = d0 * d0;
    #pragma unroll
    for (int m = 1; m < 64; m <<= 1) var += __shfl_xor(var, m, 64);
    var *= (1.f / 64.f);
    float enc = d0 * rsqrtf(var + 1e-5f) * g1[lane] + b1[lane];
    float a1 = 0.f;
    #pragma unroll
    for (int j = 0; j < 64; j++) a1 += __shfl(enc, j, 64) * f1[j * 64 + lane];
    float hrel = fmaxf(a1, 0.f);
    float a2 = 0.f;
    #pragma unroll
    for (int j = 0; j < 64; j++) a2 += __shfl(hrel, j, 64) * f2[j * 64 + lane];
    float v2 = a2 + enc;
    float mu2 = v2;
    #pragma unroll
    for (int m = 1; m < 64; m <<= 1) mu2 += __shfl_xor(mu2, m, 64);
    mu2 *= (1.f / 64.f);
    float d2 = v2 - mu2;
    float var2 = d2 * d2;
    #pragma unroll
    for (int m = 1; m < 64; m <<= 1) var2 += __shfl_xor(var2, m, 64);
    var2 *= (1.f / 64.f);
    float outv = d2 * rsqrtf(var2 + 1e-5f) * g2[lane] + b2w[lane];
    res[row * 64 + lane] = outv;
}

// ---------- launch ----------
extern "C" void kernel_launch(void* const* d_in, const int* in_sizes, int n_in,
                              void* d_out, int out_size, void* d_ws, size_t ws_size,
                              hipStream_t stream) {
    const float* x    = (const float*)d_in[0];
    const int*   mask = (const int*)d_in[1];
    const float* u    = (const float*)d_in[2];
    const float* wq   = (const float*)d_in[3];
    const float* wk   = (const float*)d_in[4];
    const float* wv   = (const float*)d_in[5];
    const float* uqw  = (const float*)d_in[6];
    const float* ukw  = (const float*)d_in[7];
    const float* uvw  = (const float*)d_in[8];
    const float* sq1  = (const float*)d_in[9];
    const float* sq2  = (const float*)d_in[10];
    const float* sk1  = (const float*)d_in[11];
    const float* sk2  = (const float*)d_in[12];
    const float* sv1  = (const float*)d_in[13];
    const float* sv2  = (const float*)d_in[14];
    const float* fcw  = (const float*)d_in[15];
    const float* g1   = (const float*)d_in[16];
    const float* b1   = (const float*)d_in[17];
    const float* f1   = (const float*)d_in[18];
    const float* f2   = (const float*)d_in[19];
    const float* g2   = (const float*)d_in[20];
    const float* b2w  = (const float*)d_in[21];

    char* ws = (char*)d_ws;
    float*        gates  = (float*)(ws + 0);
    unsigned int* mwords = (unsigned int*)(ws + 4096);              // 4,194,304 B
    ushort_t*     Qe     = (ushort_t*)(ws + 4198400);               // 16,777,216 B
    ushort_t*     Ke     = (ushort_t*)(ws + 20975616);              // 16,777,216 B
    ushort_t*     VeT    = (ushort_t*)(ws + 37752832);              //  8,388,608 B
    float*        ctx    = (float*)(ws + 46141440);                 // 16,777,216 B (end ~63 MB)

    float* res  = (float*)d_out;
    float* attn = (float*)d_out + (size_t)BB * LL * DM;             // offset 1,048,576 elems

    k_maskpack<<<dim3(4096), dim3(256), 0, stream>>>(mask, mwords);
    k_gates<<<dim3(8, 3), dim3(64), 0, stream>>>(u, sq1, sq2, sk1, sk2, sv1, sv2, gates);
    k_proj<<<dim3(64, 8), dim3(256), 0, stream>>>(x, wq, wk, wv, uqw, ukw, uvw, gates, Qe, Ke, VeT);
    k_attn<<<dim3(32, 4, 8), dim3(256), 0, stream>>>(Qe, Ke, VeT, mwords, ctx, attn);
    k_epi<<<dim3(4096), dim3(256), 0, stream>>>(ctx, x, fcw, g1, b1, f1, f2, g2, b2w, res);
}